// Round 7
// baseline (652.016 us; speedup 1.0000x reference)
//
#include <hip/hip_runtime.h>
#include <cstdint>
#include <cstddef>

// ============================================================================
// VQ-VAE encode: conv3x3(SAME) -> linear (folded) -> argmin over 8192 codes.
//
// Round 7: dispatch-count reduction + A-resident screen.
//   Evidence: screen cost ~200-250 us across 4 structurally different
//   implementations (K=768/256, sync/dbuf, conflicted/clean) -> invariant
//   ~25ns/block * 8192 blocks = workgroup dispatch overhead, not work.
//   screen5_k: 512 blocks. Block = (m-tile 128 rows) x (16 n-tiles of 128).
//     A staged once -> fragments pinned in VGPRs (af[4][8], launch_bounds
//     (256,1)); B dbuf 16KB chunks, 1 barrier/chunk; per-XCD B footprint
//     1 MB -> L2-resident. Epilogue (verified screen4 math) per n-tile.
//   refine3/packhi_s/embsq2: grid-stride, 512 blocks each.
//   convm4_k unchanged (verified, slot-permuted conflict-free).
// argmin tie-break everywhere: strict < with smaller-index preference.
// ============================================================================

#define CIN_  512
#define E_    4608
#define M_    16384

typedef _Float16 half4_t __attribute__((ext_vector_type(4)));
typedef _Float16 half8_t __attribute__((ext_vector_type(8)));
typedef float f32x4 __attribute__((ext_vector_type(4)));

#define GLOAD_LDS16(gptr, lptr)                                         \
    __builtin_amdgcn_global_load_lds(                                   \
        (const __attribute__((address_space(1))) unsigned int*)(gptr),  \
        (__attribute__((address_space(3))) unsigned int*)(lptr), 16, 0, 0)

// ---------------- transpose ----------------
__global__ void tkern(const float* __restrict__ src, float* __restrict__ dst,
                      int R, int C) {
    __shared__ float t[32][33];
    int c = blockIdx.x * 32 + threadIdx.x;
    int r = blockIdx.y * 32 + threadIdx.y;
    if (r < R && c < C) t[threadIdx.y][threadIdx.x] = src[(size_t)r * C + c];
    __syncthreads();
    int rr = blockIdx.x * 32 + threadIdx.y;
    int cc = blockIdx.y * 32 + threadIdx.x;
    if (rr < C && cc < R) dst[(size_t)rr * R + cc] = t[threadIdx.x][threadIdx.y];
}

// ---------------- fold: W2x[plane][tap][d][512c] fp16 hi/lo ----------------
__global__ __launch_bounds__(256) void fold5_k(const float* __restrict__ conv_w,
                                               const float* __restrict__ lwT,
                                               _Float16* __restrict__ W2x) {
    int e0 = blockIdx.x * 8;
    int d = threadIdx.x;
    float acc[8];
    #pragma unroll
    for (int j = 0; j < 8; ++j) acc[j] = 0.f;
    for (int co = 0; co < 256; ++co) {
        float lw = lwT[co * 256 + d];
        const float* cwr = conv_w + (size_t)co * E_ + e0;   // wave-uniform
        #pragma unroll
        for (int j = 0; j < 8; ++j) acc[j] += cwr[j] * lw;
    }
    #pragma unroll
    for (int j = 0; j < 8; ++j) {
        int e = e0 + j;
        int c = e / 9, t9 = e - c * 9;
        _Float16 h = (_Float16)acc[j];
        _Float16 l = (_Float16)(acc[j] - (float)h);
        W2x[((size_t)(t9 * 256 + d)) * 512 + c] = h;
        W2x[((size_t)((9 + t9) * 256 + d)) * 512 + c] = l;
    }
}

__global__ void bias_k(const float* __restrict__ lwT, const float* __restrict__ conv_b,
                       const float* __restrict__ lin_b, float* __restrict__ b2) {
    int d = threadIdx.x;
    float acc = lin_b[d];
    for (int co = 0; co < 256; ++co) acc += lwT[co * 256 + d] * conv_b[co];
    b2[d] = acc;
}

// ---------------- |e_k|^2, grid-stride (512 blocks) ----------------
__global__ void embsq2_k(const float* __restrict__ emb, float* __restrict__ esq) {
    int w = threadIdx.x >> 6, lane = threadIdx.x & 63;
    #pragma unroll
    for (int it = 0; it < 4; ++it) {
        int k = (blockIdx.x + it * 512) * 4 + w;
        const float* row = emb + (size_t)k * 256;
        float s = 0.f;
        #pragma unroll
        for (int i = 0; i < 4; ++i) { float v = row[lane + 64 * i]; s += v * v; }
        #pragma unroll
        for (int m = 32; m >= 1; m >>= 1) s += __shfl_xor(s, m, 64);
        if (lane == 0) esq[k] = s;
    }
}

// ---------------- latent -> channel-last fp16 hi/lo planes ----------------
__global__ __launch_bounds__(256) void packlat_k(const float* __restrict__ lat,
                                                 _Float16* __restrict__ Xnp) {
    int b = blockIdx.x, t = threadIdx.x;
    __shared__ float lt[128][65];
    const float* src = lat + (size_t)b * 512 * 64;
    _Float16* dst = Xnp + (size_t)b * 64 * 1024;
    for (int c0 = 0; c0 < 512; c0 += 128) {
        __syncthreads();
        #pragma unroll
        for (int j = 0; j < 8; ++j) {
            int f4 = t + j * 256;
            int cc = f4 >> 4, p4 = (f4 & 15) * 4;
            float4 v = *(const float4*)(src + (size_t)(c0 + cc) * 64 + p4);
            lt[cc][p4] = v.x; lt[cc][p4 + 1] = v.y;
            lt[cc][p4 + 2] = v.z; lt[cc][p4 + 3] = v.w;
        }
        __syncthreads();
        int pix = t >> 2, cr = (t & 3) * 32;
        #pragma unroll
        for (int q = 0; q < 4; ++q) {
            half8_t hh, ll;
            #pragma unroll
            for (int j = 0; j < 8; ++j) {
                float v = lt[cr + q * 8 + j][pix];
                _Float16 h = (_Float16)v;
                hh[j] = h; ll[j] = (_Float16)(v - (float)h);
            }
            *(half8_t*)(dst + (size_t)pix * 1024 + c0 + cr + q * 8) = hh;
            *(half8_t*)(dst + (size_t)pix * 1024 + 512 + c0 + cr + q * 8) = ll;
        }
    }
}

// ---------------- conv MFMA v4 (round-6, verified, conflict-free) ----------
__global__ __launch_bounds__(256) void convm4_k(
    const _Float16* __restrict__ Xnp, const _Float16* __restrict__ W2x,
    const float* __restrict__ b2, const _Float16* __restrict__ zp,
    float* __restrict__ yb) {
    __shared__ char sm[65536];
    int m0 = blockIdx.x * 128, n0 = blockIdx.y * 128;
    int tid = threadIdx.x, w = tid >> 6, lane = tid & 63;
    int wm = w & 1, wn = w >> 1;
    int fr = lane & 15, fq = lane >> 4;

    int xq = (fq ^ ((fr >> 1) & 3)) << 4;
    int aoff[4], boff[4];
    #pragma unroll
    for (int i = 0; i < 4; ++i) {
        aoff[i] = (wm * 64 + i * 16 + fr) * 64 + xq;
        boff[i] = (wn * 64 + i * 16 + fr) * 64 + xq;
    }
    int slt[2], sr[2], sq[2];
    #pragma unroll
    for (int i = 0; i < 2; ++i) {
        int s = w * 128 + i * 64 + lane;
        slt[i] = s;
        sr[i] = s >> 2;
        sq[i] = ((s & 3) ^ ((s >> 3) & 3)) * 8;
    }

    f32x4 acc[4][4];
    #pragma unroll
    for (int s = 0; s < 4; ++s)
        #pragma unroll
        for (int t = 0; t < 4; ++t)
            #pragma unroll
            for (int r = 0; r < 4; ++r) acc[s][t][r] = 0.f;

    auto stage = [&](int it, int buf) {
        int tap = it >> 4, cc = it & 15;
        int dy = tap / 3 - 1, dx = tap - (tap / 3) * 3 - 1;
        char* L = sm + buf * 32768;
        #pragma unroll
        for (int i = 0; i < 2; ++i) {
            int choff = cc * 32 + sq[i];
            int gm = m0 + sr[i];
            int img = gm >> 6, pix = gm & 63;
            int ih = (pix >> 3) + dy, iw = (pix & 7) + dx;
            bool v = ((unsigned)ih < 8u) && ((unsigned)iw < 8u);
            const _Float16* a0 = v
                ? Xnp + ((size_t)(img * 64 + ih * 8 + iw)) * 1024 : zp;
            const _Float16* a1 = v ? a0 + 512 : zp;
            GLOAD_LDS16(a0 + choff, L + slt[i] * 16);
            GLOAD_LDS16(a1 + choff, L + 8192 + slt[i] * 16);
            const _Float16* bb =
                W2x + ((size_t)(tap * 256 + n0 + sr[i])) * 512 + choff;
            GLOAD_LDS16(bb, L + 16384 + slt[i] * 16);
            GLOAD_LDS16(bb + (size_t)9 * 256 * 512, L + 24576 + slt[i] * 16);
        }
    };

    stage(0, 0);
    for (int it = 0; it < 144; ++it) {
        __syncthreads();
        if (it + 1 < 144) stage(it + 1, (it + 1) & 1);
        const char* L = sm + (it & 1) * 32768;
        half8_t ah[4], al[4], bh[4], bl[4];
        #pragma unroll
        for (int s = 0; s < 4; ++s) ah[s] = *(const half8_t*)(L + aoff[s]);
        #pragma unroll
        for (int t = 0; t < 4; ++t) bh[t] = *(const half8_t*)(L + 16384 + boff[t]);
        #pragma unroll
        for (int s = 0; s < 4; ++s)
            #pragma unroll
            for (int t = 0; t < 4; ++t)
                acc[s][t] = __builtin_amdgcn_mfma_f32_16x16x32_f16(
                    ah[s], bh[t], acc[s][t], 0, 0, 0);
        #pragma unroll
        for (int t = 0; t < 4; ++t) bl[t] = *(const half8_t*)(L + 24576 + boff[t]);
        #pragma unroll
        for (int s = 0; s < 4; ++s)
            #pragma unroll
            for (int t = 0; t < 4; ++t)
                acc[s][t] = __builtin_amdgcn_mfma_f32_16x16x32_f16(
                    ah[s], bl[t], acc[s][t], 0, 0, 0);
        #pragma unroll
        for (int s = 0; s < 4; ++s) al[s] = *(const half8_t*)(L + 8192 + aoff[s]);
        #pragma unroll
        for (int s = 0; s < 4; ++s)
            #pragma unroll
            for (int t = 0; t < 4; ++t)
                acc[s][t] = __builtin_amdgcn_mfma_f32_16x16x32_f16(
                    al[s], bh[t], acc[s][t], 0, 0, 0);
    }

    float bv[4];
    #pragma unroll
    for (int t = 0; t < 4; ++t) bv[t] = b2[n0 + wn * 64 + t * 16 + fr];
    #pragma unroll
    for (int s = 0; s < 4; ++s)
        #pragma unroll
        for (int r = 0; r < 4; ++r) {
            int m = m0 + wm * 64 + s * 16 + fq * 4 + r;
            #pragma unroll
            for (int t = 0; t < 4; ++t) {
                int d = n0 + wn * 64 + t * 16 + fr;
                yb[(size_t)m * 256 + d] = acc[s][t][r] + bv[t];
            }
        }
}

// ---------------- fp32 -> fp16 hi pack, grid-stride ----------------
__global__ void packhi_s(const float* __restrict__ x, _Float16* __restrict__ o,
                         int iters) {
    for (int it = 0; it < iters; ++it) {
        int i = (blockIdx.x + it * 512) * 256 + threadIdx.x;
        float4 v = *(const float4*)(x + (size_t)i * 4);
        half4_t h = {(_Float16)v.x, (_Float16)v.y, (_Float16)v.z, (_Float16)v.w};
        *(half4_t*)(o + (size_t)i * 4) = h;
    }
}

// ---------------- MFMA screen v5: A-resident, 512 blocks ----------------
// Block = (m-tile mt = bx>>2: 128 rows) x (n-group ng = bx&3: 16 n-tiles of
// 128 codes). A frags pinned in VGPR; B dbuf 16 KB chunks (BK=64).
// LDS: A 4 sections x 16 KB (dead after prologue) + B 2 x 16 KB = 96 KB.
#define SCR_LDS 98304
__global__ __launch_bounds__(256, 1) void screen5_k(
    const _Float16* __restrict__ A2, const _Float16* __restrict__ B2,
    const float* __restrict__ esq, float* __restrict__ ps2, int* __restrict__ pi2) {
    extern __shared__ char sm[];
    int mt = blockIdx.x >> 2, ng = blockIdx.x & 3;
    int m0 = mt * 128;
    int tid = threadIdx.x, w = tid >> 6, lane = tid & 63;
    int wm = w & 1, wn = w >> 1;
    int fr = lane & 15, fq = lane >> 4;

    // staging slot geometry (per 16 KB section): 4 GLOADs per wave
    int slt[4], sr[4], sq[4];
    #pragma unroll
    for (int i = 0; i < 4; ++i) {
        int s = w * 256 + i * 64 + lane;
        slt[i] = s;
        sr[i] = s >> 3;
        sq[i] = ((s & 7) ^ ((s >> 3) & 7)) * 8;
    }
    // fragment read geometry (verified screen4 math)
    int xq8[2];
    #pragma unroll
    for (int kk = 0; kk < 2; ++kk) xq8[kk] = ((kk * 4 + fq) ^ (fr & 7)) << 4;
    int arow[4], brow[4];
    #pragma unroll
    for (int i = 0; i < 4; ++i) {
        arow[i] = (wm * 64 + i * 16 + fr) * 128;
        brow[i] = (wn * 64 + i * 16 + fr) * 128;
    }

    // stage A (4 sections of BK=64)
    #pragma unroll
    for (int kt = 0; kt < 4; ++kt)
        #pragma unroll
        for (int i = 0; i < 4; ++i)
            GLOAD_LDS16(A2 + (size_t)(m0 + sr[i]) * 256 + kt * 64 + sq[i],
                        sm + kt * 16384 + slt[i] * 16);

    char* Bb = sm + 65536;
    auto stageB = [&](int q) {
        int j = q >> 2, kt = q & 3, buf = q & 1;
        int n0 = (ng * 16 + j) * 128;
        #pragma unroll
        for (int i = 0; i < 4; ++i)
            GLOAD_LDS16(B2 + (size_t)(n0 + sr[i]) * 256 + kt * 64 + sq[i],
                        Bb + buf * 16384 + slt[i] * 16);
    };
    stageB(0);
    __syncthreads();           // drains A sections + B chunk 0

    // pin A fragments in VGPRs: af[s][kt*2+kk]
    half8_t af[4][8];
    #pragma unroll
    for (int kt = 0; kt < 4; ++kt)
        #pragma unroll
        for (int kk = 0; kk < 2; ++kk)
            #pragma unroll
            for (int s = 0; s < 4; ++s)
                af[s][kt * 2 + kk] =
                    *(const half8_t*)(sm + kt * 16384 + arow[s] + xq8[kk]);

    f32x4 acc[4][4];
    #pragma unroll
    for (int s = 0; s < 4; ++s)
        #pragma unroll
        for (int t = 0; t < 4; ++t)
            #pragma unroll
            for (int r = 0; r < 4; ++r) acc[s][t][r] = 0.f;

    float esv[4];
    for (int j = 0; j < 16; ++j) {
        int n0 = (ng * 16 + j) * 128;
        #pragma unroll
        for (int kt = 0; kt < 4; ++kt) {
            int q = j * 4 + kt;
            __syncthreads();
            if (q + 1 < 64) stageB(q + 1);
            if (kt == 0) {     // prefetch esq for this n-tile's epilogue
                #pragma unroll
                for (int t = 0; t < 4; ++t)
                    esv[t] = esq[n0 + wn * 64 + t * 16 + fr];
            }
            const char* L = Bb + (q & 1) * 16384;
            #pragma unroll
            for (int kk = 0; kk < 2; ++kk) {
                half8_t bf[4];
                #pragma unroll
                for (int t = 0; t < 4; ++t)
                    bf[t] = *(const half8_t*)(L + brow[t] + xq8[kk]);
                #pragma unroll
                for (int s = 0; s < 4; ++s)
                    #pragma unroll
                    for (int t = 0; t < 4; ++t)
                        acc[s][t] = __builtin_amdgcn_mfma_f32_16x16x32_f16(
                            af[s][kt * 2 + kk], bf[t], acc[s][t], 0, 0, 0);
            }
        }
        // epilogue for n-tile j (verified screen4 math)
        int colIdx = (ng * 16 + j) * 2 + wn;
        #pragma unroll
        for (int s = 0; s < 4; ++s) {
            #pragma unroll
            for (int r = 0; r < 4; ++r) {
                float best = 3.4e38f; int bidx = 0x7fffffff;
                #pragma unroll
                for (int t = 0; t < 4; ++t) {
                    float sc = esv[t] - 2.f * acc[s][t][r];
                    int k = n0 + wn * 64 + t * 16 + fr;
                    if (sc < best || (sc == best && k < bidx)) { best = sc; bidx = k; }
                }
                #pragma unroll
                for (int msk = 1; msk <= 8; msk <<= 1) {
                    float so = __shfl_xor(best, msk, 64);
                    int ko2 = __shfl_xor(bidx, msk, 64);
                    if (so < best || (so == best && ko2 < bidx)) { best = so; bidx = ko2; }
                }
                if (fr == 0) {
                    int m = m0 + wm * 64 + s * 16 + fq * 4 + r;
                    ps2[(size_t)m * 128 + colIdx] = best;
                    pi2[(size_t)m * 128 + colIdx] = bidx;
                }
            }
        }
        // reset accumulator for next n-tile
        #pragma unroll
        for (int s = 0; s < 4; ++s)
            #pragma unroll
            for (int t = 0; t < 4; ++t)
                #pragma unroll
                for (int r = 0; r < 4; ++r) acc[s][t][r] = 0.f;
    }
}

// ---------------- exact fp32 refine, grid-stride (512 blocks) ----------------
__global__ __launch_bounds__(256) void refine3_k(
    const float* __restrict__ y, const float* __restrict__ emb,
    const float* __restrict__ esq, const float* __restrict__ ps2,
    const int* __restrict__ pi2, int* __restrict__ out) {
    int lane = threadIdx.x & 63;
    for (int j = 0; j < 8; ++j) {
        int m = blockIdx.x * 32 + j * 4 + (threadIdx.x >> 6);
        float4 yv = *(const float4*)(y + (size_t)m * 256 + lane * 4);
        float sc_[2]; int kc_[2];
        #pragma unroll
        for (int i = 0; i < 2; ++i) {
            sc_[i] = ps2[(size_t)m * 128 + lane * 2 + i];
            kc_[i] = pi2[(size_t)m * 128 + lane * 2 + i];
        }
        float s0 = fminf(sc_[0], sc_[1]);
        #pragma unroll
        for (int msk = 1; msk <= 32; msk <<= 1) s0 = fminf(s0, __shfl_xor(s0, msk, 64));
        float thr = s0 + 0.25f;
        float best = 3.4e38f; int bk = 0x7fffffff;
        for (int c = 0; c < 128; ++c) {
            float scc = __shfl(sc_[c & 1], c >> 1, 64);
            if (scc <= thr) {            // wave-uniform
                int k = __shfl(kc_[c & 1], c >> 1, 64);
                float4 ev = *(const float4*)(emb + (size_t)k * 256 + lane * 4);
                float d = yv.x * ev.x + yv.y * ev.y + yv.z * ev.z + yv.w * ev.w;
                #pragma unroll
                for (int msk = 1; msk <= 32; msk <<= 1) d += __shfl_xor(d, msk, 64);
                float sx = esq[k] - 2.f * d;
                if (sx < best || (sx == best && k < bk)) { best = sx; bk = k; }
            }
        }
        if (lane == 0) out[m] = bk;
    }
}

extern "C" void kernel_launch(void* const* d_in, const int* in_sizes, int n_in,
                              void* d_out, int out_size, void* d_ws, size_t ws_size,
                              hipStream_t stream) {
    const float* latent = (const float*)d_in[0];
    const float* conv_w = (const float*)d_in[1];
    const float* conv_b = (const float*)d_in[2];
    const float* lin_w  = (const float*)d_in[3];
    const float* lin_b  = (const float*)d_in[4];
    const float* emb    = (const float*)d_in[5];
    int* out = (int*)d_out;

    char* W = (char*)d_ws;                           // proven 55.35 MB budget
    float*    lwT = (float*)(W + 0);                 //   262,144
    float*    b2  = (float*)(W + 262144);            //     1,024
    float*    esq = (float*)(W + 263168);            //    32,768
    float*    yb  = (float*)(W + 295936);            // 16,777,216
    _Float16* W2x = (_Float16*)(W + 17073152);       //  4,718,592
    _Float16* zp  = (_Float16*)(W + 21791744);       //     1,024
    _Float16* Xnp = (_Float16*)(W + 21792768);       // 33,554,432 (conv-time)
    // post-conv aliases on the Xnp region:
    _Float16* A2  = (_Float16*)(W + 21792768);       //  8,388,608
    _Float16* B2  = (_Float16*)(W + 30181376);       //  4,194,304
    float*    ps2 = (float*)(W + 34375680);          //  8,388,608
    int*      pi2 = (int*)(W + 42764288);            //  8,388,608 -> 51,152,896

    dim3 t32(32, 32);
    tkern<<<dim3(8, 8), t32, 0, stream>>>(lin_w, lwT, 256, 256);
    bias_k<<<1, 256, 0, stream>>>(lwT, conv_b, lin_b, b2);
    embsq2_k<<<512, 256, 0, stream>>>(emb, esq);
    fold5_k<<<576, 256, 0, stream>>>(conv_w, lwT, W2x);
    hipMemsetAsync(zp, 0, 1024, stream);
    packlat_k<<<256, 256, 0, stream>>>(latent, Xnp);

    convm4_k<<<dim3(128, 2), 256, 0, stream>>>(Xnp, W2x, b2, zp, yb);

    packhi_s<<<512, 256, 0, stream>>>(yb, A2, 8);    // 16384x256 (Xnp dead)
    packhi_s<<<512, 256, 0, stream>>>(emb, B2, 4);   // 8192x256
    screen5_k<<<512, 256, SCR_LDS, stream>>>(A2, B2, esq, ps2, pi2);
    refine3_k<<<512, 256, 0, stream>>>(yb, emb, esq, ps2, pi2, out);
}

// Round 8
// 505.659 us; speedup vs baseline: 1.2894x; 1.2894x over previous
//
#include <hip/hip_runtime.h>
#include <cstdint>
#include <cstddef>

// ============================================================================
// VQ-VAE encode: conv3x3(SAME) -> linear (folded) -> argmin over 8192 codes.
//
// Round 8: screen back to 8192 blocks, BK=32, 32 KB LDS -> 4-5 blocks/CU.
//   R7 evidence: screen time tracks resident blocks/CU (1/CU=300us, 2/CU=218us)
//   -> barrier-drain latency is the bottleneck; co-resident blocks hide it.
//   screen6_k: screen4's verified math, BK=32 dbuf (2 x (8KB A + 8KB B)),
//   slot-permuted staging (convm4-verified, conflict-free), 8 iters x 1 barrier.
//   convm4_k / smalls unchanged from R7.
// argmin tie-break everywhere: strict < with smaller-index preference.
// ============================================================================

#define CIN_  512
#define E_    4608
#define M_    16384

typedef _Float16 half4_t __attribute__((ext_vector_type(4)));
typedef _Float16 half8_t __attribute__((ext_vector_type(8)));
typedef float f32x4 __attribute__((ext_vector_type(4)));

#define GLOAD_LDS16(gptr, lptr)                                         \
    __builtin_amdgcn_global_load_lds(                                   \
        (const __attribute__((address_space(1))) unsigned int*)(gptr),  \
        (__attribute__((address_space(3))) unsigned int*)(lptr), 16, 0, 0)

// ---------------- transpose ----------------
__global__ void tkern(const float* __restrict__ src, float* __restrict__ dst,
                      int R, int C) {
    __shared__ float t[32][33];
    int c = blockIdx.x * 32 + threadIdx.x;
    int r = blockIdx.y * 32 + threadIdx.y;
    if (r < R && c < C) t[threadIdx.y][threadIdx.x] = src[(size_t)r * C + c];
    __syncthreads();
    int rr = blockIdx.x * 32 + threadIdx.y;
    int cc = blockIdx.y * 32 + threadIdx.x;
    if (rr < C && cc < R) dst[(size_t)rr * R + cc] = t[threadIdx.x][threadIdx.y];
}

// ---------------- fold: W2x[plane][tap][d][512c] fp16 hi/lo ----------------
__global__ __launch_bounds__(256) void fold5_k(const float* __restrict__ conv_w,
                                               const float* __restrict__ lwT,
                                               _Float16* __restrict__ W2x) {
    int e0 = blockIdx.x * 8;
    int d = threadIdx.x;
    float acc[8];
    #pragma unroll
    for (int j = 0; j < 8; ++j) acc[j] = 0.f;
    for (int co = 0; co < 256; ++co) {
        float lw = lwT[co * 256 + d];
        const float* cwr = conv_w + (size_t)co * E_ + e0;   // wave-uniform
        #pragma unroll
        for (int j = 0; j < 8; ++j) acc[j] += cwr[j] * lw;
    }
    #pragma unroll
    for (int j = 0; j < 8; ++j) {
        int e = e0 + j;
        int c = e / 9, t9 = e - c * 9;
        _Float16 h = (_Float16)acc[j];
        _Float16 l = (_Float16)(acc[j] - (float)h);
        W2x[((size_t)(t9 * 256 + d)) * 512 + c] = h;
        W2x[((size_t)((9 + t9) * 256 + d)) * 512 + c] = l;
    }
}

__global__ void bias_k(const float* __restrict__ lwT, const float* __restrict__ conv_b,
                       const float* __restrict__ lin_b, float* __restrict__ b2) {
    int d = threadIdx.x;
    float acc = lin_b[d];
    for (int co = 0; co < 256; ++co) acc += lwT[co * 256 + d] * conv_b[co];
    b2[d] = acc;
}

// ---------------- |e_k|^2, grid-stride (512 blocks) ----------------
__global__ void embsq2_k(const float* __restrict__ emb, float* __restrict__ esq) {
    int w = threadIdx.x >> 6, lane = threadIdx.x & 63;
    #pragma unroll
    for (int it = 0; it < 4; ++it) {
        int k = (blockIdx.x + it * 512) * 4 + w;
        const float* row = emb + (size_t)k * 256;
        float s = 0.f;
        #pragma unroll
        for (int i = 0; i < 4; ++i) { float v = row[lane + 64 * i]; s += v * v; }
        #pragma unroll
        for (int m = 32; m >= 1; m >>= 1) s += __shfl_xor(s, m, 64);
        if (lane == 0) esq[k] = s;
    }
}

// ---------------- latent -> channel-last fp16 hi/lo planes ----------------
__global__ __launch_bounds__(256) void packlat_k(const float* __restrict__ lat,
                                                 _Float16* __restrict__ Xnp) {
    int b = blockIdx.x, t = threadIdx.x;
    __shared__ float lt[128][65];
    const float* src = lat + (size_t)b * 512 * 64;
    _Float16* dst = Xnp + (size_t)b * 64 * 1024;
    for (int c0 = 0; c0 < 512; c0 += 128) {
        __syncthreads();
        #pragma unroll
        for (int j = 0; j < 8; ++j) {
            int f4 = t + j * 256;
            int cc = f4 >> 4, p4 = (f4 & 15) * 4;
            float4 v = *(const float4*)(src + (size_t)(c0 + cc) * 64 + p4);
            lt[cc][p4] = v.x; lt[cc][p4 + 1] = v.y;
            lt[cc][p4 + 2] = v.z; lt[cc][p4 + 3] = v.w;
        }
        __syncthreads();
        int pix = t >> 2, cr = (t & 3) * 32;
        #pragma unroll
        for (int q = 0; q < 4; ++q) {
            half8_t hh, ll;
            #pragma unroll
            for (int j = 0; j < 8; ++j) {
                float v = lt[cr + q * 8 + j][pix];
                _Float16 h = (_Float16)v;
                hh[j] = h; ll[j] = (_Float16)(v - (float)h);
            }
            *(half8_t*)(dst + (size_t)pix * 1024 + c0 + cr + q * 8) = hh;
            *(half8_t*)(dst + (size_t)pix * 1024 + 512 + c0 + cr + q * 8) = ll;
        }
    }
}

// ---------------- conv MFMA v4 (round-6, verified, conflict-free) ----------
__global__ __launch_bounds__(256) void convm4_k(
    const _Float16* __restrict__ Xnp, const _Float16* __restrict__ W2x,
    const float* __restrict__ b2, const _Float16* __restrict__ zp,
    float* __restrict__ yb) {
    __shared__ char sm[65536];
    int m0 = blockIdx.x * 128, n0 = blockIdx.y * 128;
    int tid = threadIdx.x, w = tid >> 6, lane = tid & 63;
    int wm = w & 1, wn = w >> 1;
    int fr = lane & 15, fq = lane >> 4;

    int xq = (fq ^ ((fr >> 1) & 3)) << 4;
    int aoff[4], boff[4];
    #pragma unroll
    for (int i = 0; i < 4; ++i) {
        aoff[i] = (wm * 64 + i * 16 + fr) * 64 + xq;
        boff[i] = (wn * 64 + i * 16 + fr) * 64 + xq;
    }
    int slt[2], sr[2], sq[2];
    #pragma unroll
    for (int i = 0; i < 2; ++i) {
        int s = w * 128 + i * 64 + lane;
        slt[i] = s;
        sr[i] = s >> 2;
        sq[i] = ((s & 3) ^ ((s >> 3) & 3)) * 8;
    }

    f32x4 acc[4][4];
    #pragma unroll
    for (int s = 0; s < 4; ++s)
        #pragma unroll
        for (int t = 0; t < 4; ++t)
            #pragma unroll
            for (int r = 0; r < 4; ++r) acc[s][t][r] = 0.f;

    auto stage = [&](int it, int buf) {
        int tap = it >> 4, cc = it & 15;
        int dy = tap / 3 - 1, dx = tap - (tap / 3) * 3 - 1;
        char* L = sm + buf * 32768;
        #pragma unroll
        for (int i = 0; i < 2; ++i) {
            int choff = cc * 32 + sq[i];
            int gm = m0 + sr[i];
            int img = gm >> 6, pix = gm & 63;
            int ih = (pix >> 3) + dy, iw = (pix & 7) + dx;
            bool v = ((unsigned)ih < 8u) && ((unsigned)iw < 8u);
            const _Float16* a0 = v
                ? Xnp + ((size_t)(img * 64 + ih * 8 + iw)) * 1024 : zp;
            const _Float16* a1 = v ? a0 + 512 : zp;
            GLOAD_LDS16(a0 + choff, L + slt[i] * 16);
            GLOAD_LDS16(a1 + choff, L + 8192 + slt[i] * 16);
            const _Float16* bb =
                W2x + ((size_t)(tap * 256 + n0 + sr[i])) * 512 + choff;
            GLOAD_LDS16(bb, L + 16384 + slt[i] * 16);
            GLOAD_LDS16(bb + (size_t)9 * 256 * 512, L + 24576 + slt[i] * 16);
        }
    };

    stage(0, 0);
    for (int it = 0; it < 144; ++it) {
        __syncthreads();
        if (it + 1 < 144) stage(it + 1, (it + 1) & 1);
        const char* L = sm + (it & 1) * 32768;
        half8_t ah[4], al[4], bh[4], bl[4];
        #pragma unroll
        for (int s = 0; s < 4; ++s) ah[s] = *(const half8_t*)(L + aoff[s]);
        #pragma unroll
        for (int t = 0; t < 4; ++t) bh[t] = *(const half8_t*)(L + 16384 + boff[t]);
        #pragma unroll
        for (int s = 0; s < 4; ++s)
            #pragma unroll
            for (int t = 0; t < 4; ++t)
                acc[s][t] = __builtin_amdgcn_mfma_f32_16x16x32_f16(
                    ah[s], bh[t], acc[s][t], 0, 0, 0);
        #pragma unroll
        for (int t = 0; t < 4; ++t) bl[t] = *(const half8_t*)(L + 24576 + boff[t]);
        #pragma unroll
        for (int s = 0; s < 4; ++s)
            #pragma unroll
            for (int t = 0; t < 4; ++t)
                acc[s][t] = __builtin_amdgcn_mfma_f32_16x16x32_f16(
                    ah[s], bl[t], acc[s][t], 0, 0, 0);
        #pragma unroll
        for (int s = 0; s < 4; ++s) al[s] = *(const half8_t*)(L + 8192 + aoff[s]);
        #pragma unroll
        for (int s = 0; s < 4; ++s)
            #pragma unroll
            for (int t = 0; t < 4; ++t)
                acc[s][t] = __builtin_amdgcn_mfma_f32_16x16x32_f16(
                    al[s], bh[t], acc[s][t], 0, 0, 0);
    }

    float bv[4];
    #pragma unroll
    for (int t = 0; t < 4; ++t) bv[t] = b2[n0 + wn * 64 + t * 16 + fr];
    #pragma unroll
    for (int s = 0; s < 4; ++s)
        #pragma unroll
        for (int r = 0; r < 4; ++r) {
            int m = m0 + wm * 64 + s * 16 + fq * 4 + r;
            #pragma unroll
            for (int t = 0; t < 4; ++t) {
                int d = n0 + wn * 64 + t * 16 + fr;
                yb[(size_t)m * 256 + d] = acc[s][t][r] + bv[t];
            }
        }
}

// ---------------- fp32 -> fp16 hi pack, grid-stride ----------------
__global__ void packhi_s(const float* __restrict__ x, _Float16* __restrict__ o,
                         int iters) {
    for (int it = 0; it < iters; ++it) {
        int i = (blockIdx.x + it * 512) * 256 + threadIdx.x;
        float4 v = *(const float4*)(x + (size_t)i * 4);
        half4_t h = {(_Float16)v.x, (_Float16)v.y, (_Float16)v.z, (_Float16)v.w};
        *(half4_t*)(o + (size_t)i * 4) = h;
    }
}

// ---------------- MFMA screen v6: BK=32, 32 KB LDS, 4-5 blocks/CU ----------
// grid (128 m-tiles, 64 n-tiles), 256 thr = 4 waves (2x2 of 64x64).
// LDS: 2 bufs x (A 8KB + B 8KB). 8 kt-iters x 1 barrier.
__global__ __launch_bounds__(256) void screen6_k(
    const _Float16* __restrict__ A2, const _Float16* __restrict__ B2,
    const float* __restrict__ esq, float* __restrict__ ps2, int* __restrict__ pi2) {
    __shared__ char sm[32768];
    int m0 = blockIdx.x * 128, n0 = blockIdx.y * 128;
    int tid = threadIdx.x, w = tid >> 6, lane = tid & 63;
    int wm = w & 1, wn = w >> 1;
    int fr = lane & 15, fq = lane >> 4;

    // fragment-read offsets (BK=32 slot-permuted layout; convm4-verified)
    int xq = (fq ^ ((fr >> 1) & 3)) << 4;
    int aoff[4], boff[4];
    #pragma unroll
    for (int i = 0; i < 4; ++i) {
        aoff[i] = (wm * 64 + i * 16 + fr) * 64 + xq;
        boff[i] = (wn * 64 + i * 16 + fr) * 64 + xq;
    }
    // staging slot geometry (2 GLOADs per tile per wave)
    int slt[2], sr[2], sq[2];
    #pragma unroll
    for (int i = 0; i < 2; ++i) {
        int s = w * 128 + i * 64 + lane;
        slt[i] = s;
        sr[i] = s >> 2;
        sq[i] = ((s & 3) ^ ((s >> 3) & 3)) * 8;
    }

    auto stage = [&](int kt, int buf) {
        char* L = sm + buf * 16384;
        int ko = kt * 32;
        #pragma unroll
        for (int i = 0; i < 2; ++i) {
            GLOAD_LDS16(A2 + (size_t)(m0 + sr[i]) * 256 + ko + sq[i],
                        L + slt[i] * 16);
            GLOAD_LDS16(B2 + (size_t)(n0 + sr[i]) * 256 + ko + sq[i],
                        L + 8192 + slt[i] * 16);
        }
    };

    f32x4 acc[4][4];
    #pragma unroll
    for (int s = 0; s < 4; ++s)
        #pragma unroll
        for (int t = 0; t < 4; ++t)
            #pragma unroll
            for (int r = 0; r < 4; ++r) acc[s][t][r] = 0.f;

    stage(0, 0);
    for (int kt = 0; kt < 8; ++kt) {
        __syncthreads();
        if (kt + 1 < 8) stage(kt + 1, (kt + 1) & 1);
        const char* L = sm + (kt & 1) * 16384;
        half8_t af[4], bf[4];
        #pragma unroll
        for (int s = 0; s < 4; ++s) af[s] = *(const half8_t*)(L + aoff[s]);
        #pragma unroll
        for (int t = 0; t < 4; ++t) bf[t] = *(const half8_t*)(L + 8192 + boff[t]);
        #pragma unroll
        for (int s = 0; s < 4; ++s)
            #pragma unroll
            for (int t = 0; t < 4; ++t)
                acc[s][t] = __builtin_amdgcn_mfma_f32_16x16x32_f16(
                    af[s], bf[t], acc[s][t], 0, 0, 0);
    }

    // epilogue (screen4-verified math)
    float esv[4];
    #pragma unroll
    for (int t = 0; t < 4; ++t) esv[t] = esq[n0 + wn * 64 + t * 16 + fr];
    int colIdx = blockIdx.y * 2 + wn;
    #pragma unroll
    for (int s = 0; s < 4; ++s) {
        #pragma unroll
        for (int r = 0; r < 4; ++r) {
            float best = 3.4e38f; int bidx = 0x7fffffff;
            #pragma unroll
            for (int t = 0; t < 4; ++t) {
                float sc = esv[t] - 2.f * acc[s][t][r];
                int k = n0 + wn * 64 + t * 16 + fr;
                if (sc < best || (sc == best && k < bidx)) { best = sc; bidx = k; }
            }
            #pragma unroll
            for (int msk = 1; msk <= 8; msk <<= 1) {
                float so = __shfl_xor(best, msk, 64);
                int ko2 = __shfl_xor(bidx, msk, 64);
                if (so < best || (so == best && ko2 < bidx)) { best = so; bidx = ko2; }
            }
            if (fr == 0) {
                int m = m0 + wm * 64 + s * 16 + fq * 4 + r;
                ps2[(size_t)m * 128 + colIdx] = best;
                pi2[(size_t)m * 128 + colIdx] = bidx;
            }
        }
    }
}

// ---------------- exact fp32 refine, grid-stride (512 blocks) ----------------
__global__ __launch_bounds__(256) void refine3_k(
    const float* __restrict__ y, const float* __restrict__ emb,
    const float* __restrict__ esq, const float* __restrict__ ps2,
    const int* __restrict__ pi2, int* __restrict__ out) {
    int lane = threadIdx.x & 63;
    for (int j = 0; j < 8; ++j) {
        int m = blockIdx.x * 32 + j * 4 + (threadIdx.x >> 6);
        float4 yv = *(const float4*)(y + (size_t)m * 256 + lane * 4);
        float sc_[2]; int kc_[2];
        #pragma unroll
        for (int i = 0; i < 2; ++i) {
            sc_[i] = ps2[(size_t)m * 128 + lane * 2 + i];
            kc_[i] = pi2[(size_t)m * 128 + lane * 2 + i];
        }
        float s0 = fminf(sc_[0], sc_[1]);
        #pragma unroll
        for (int msk = 1; msk <= 32; msk <<= 1) s0 = fminf(s0, __shfl_xor(s0, msk, 64));
        float thr = s0 + 0.25f;
        float best = 3.4e38f; int bk = 0x7fffffff;
        for (int c = 0; c < 128; ++c) {
            float scc = __shfl(sc_[c & 1], c >> 1, 64);
            if (scc <= thr) {            // wave-uniform
                int k = __shfl(kc_[c & 1], c >> 1, 64);
                float4 ev = *(const float4*)(emb + (size_t)k * 256 + lane * 4);
                float d = yv.x * ev.x + yv.y * ev.y + yv.z * ev.z + yv.w * ev.w;
                #pragma unroll
                for (int msk = 1; msk <= 32; msk <<= 1) d += __shfl_xor(d, msk, 64);
                float sx = esq[k] - 2.f * d;
                if (sx < best || (sx == best && k < bk)) { best = sx; bk = k; }
            }
        }
        if (lane == 0) out[m] = bk;
    }
}

extern "C" void kernel_launch(void* const* d_in, const int* in_sizes, int n_in,
                              void* d_out, int out_size, void* d_ws, size_t ws_size,
                              hipStream_t stream) {
    const float* latent = (const float*)d_in[0];
    const float* conv_w = (const float*)d_in[1];
    const float* conv_b = (const float*)d_in[2];
    const float* lin_w  = (const float*)d_in[3];
    const float* lin_b  = (const float*)d_in[4];
    const float* emb    = (const float*)d_in[5];
    int* out = (int*)d_out;

    char* W = (char*)d_ws;                           // proven 55.35 MB budget
    float*    lwT = (float*)(W + 0);                 //   262,144
    float*    b2  = (float*)(W + 262144);            //     1,024
    float*    esq = (float*)(W + 263168);            //    32,768
    float*    yb  = (float*)(W + 295936);            // 16,777,216
    _Float16* W2x = (_Float16*)(W + 17073152);       //  4,718,592
    _Float16* zp  = (_Float16*)(W + 21791744);       //     1,024
    _Float16* Xnp = (_Float16*)(W + 21792768);       // 33,554,432 (conv-time)
    // post-conv aliases on the Xnp region:
    _Float16* A2  = (_Float16*)(W + 21792768);       //  8,388,608
    _Float16* B2  = (_Float16*)(W + 30181376);       //  4,194,304
    float*    ps2 = (float*)(W + 34375680);          //  8,388,608
    int*      pi2 = (int*)(W + 42764288);            //  8,388,608 -> 51,152,896

    dim3 t32(32, 32);
    tkern<<<dim3(8, 8), t32, 0, stream>>>(lin_w, lwT, 256, 256);
    bias_k<<<1, 256, 0, stream>>>(lwT, conv_b, lin_b, b2);
    embsq2_k<<<512, 256, 0, stream>>>(emb, esq);
    fold5_k<<<576, 256, 0, stream>>>(conv_w, lwT, W2x);
    hipMemsetAsync(zp, 0, 1024, stream);
    packlat_k<<<256, 256, 0, stream>>>(latent, Xnp);

    convm4_k<<<dim3(128, 2), 256, 0, stream>>>(Xnp, W2x, b2, zp, yb);

    packhi_s<<<512, 256, 0, stream>>>(yb, A2, 8);    // 16384x256 (Xnp dead)
    packhi_s<<<512, 256, 0, stream>>>(emb, B2, 4);   // 8192x256
    screen6_k<<<dim3(128, 64), 256, 0, stream>>>(A2, B2, esq, ps2, pi2);
    refine3_k<<<512, 256, 0, stream>>>(yb, emb, esq, ps2, pi2, out);
}

// Round 10
// 473.809 us; speedup vs baseline: 1.3761x; 1.0672x over previous
//
#include <hip/hip_runtime.h>
#include <cstdint>
#include <cstddef>

// ============================================================================
// VQ-VAE encode: conv3x3(SAME) -> linear (folded) -> argmin over 8192 codes.
//
// Round 10: R9's structural wins with the aliasing bugs removed.
//   BUG POST-MORTEM (R9, absmax 8134): (1) embpack wrote B2 (aliases Xnp)
//   BEFORE packlat overwrote the region -> screen scored garbage codes.
//   (2) convm6's fused A2 epilogue wrote into live Xnp (inter-block WAR race).
//   FIX: convm6 writes yb only; pack2_k (after convm6, Xnp dead) packs
//   A2<-yb, B2<-emb, esq<-emb in one dispatch. R8-proven liveness ordering.
//   convm6_k: tap-amplification-free conv (A chunk staged once, 9 taps via
//     in-LDS shifted fragment reads, B hi/lo streamed dbuf; 64 KB static).
//   screen7_k: XCD-aware remap (xcd=L&7 owns 16 m-tiles, n-major sweep).
//   refine3_k: exact fp32 re-score of candidates within 0.25 of screen min.
// argmin tie-break everywhere: strict < with smaller-index preference.
// ============================================================================

#define CIN_  512
#define E_    4608
#define M_    16384

typedef _Float16 half4_t __attribute__((ext_vector_type(4)));
typedef _Float16 half8_t __attribute__((ext_vector_type(8)));
typedef float f32x4 __attribute__((ext_vector_type(4)));

#define GLOAD_LDS16(gptr, lptr)                                         \
    __builtin_amdgcn_global_load_lds(                                   \
        (const __attribute__((address_space(1))) unsigned int*)(gptr),  \
        (__attribute__((address_space(3))) unsigned int*)(lptr), 16, 0, 0)

// ---------------- transpose ----------------
__global__ void tkern(const float* __restrict__ src, float* __restrict__ dst,
                      int R, int C) {
    __shared__ float t[32][33];
    int c = blockIdx.x * 32 + threadIdx.x;
    int r = blockIdx.y * 32 + threadIdx.y;
    if (r < R && c < C) t[threadIdx.y][threadIdx.x] = src[(size_t)r * C + c];
    __syncthreads();
    int rr = blockIdx.x * 32 + threadIdx.y;
    int cc = blockIdx.y * 32 + threadIdx.x;
    if (rr < C && cc < R) dst[(size_t)rr * R + cc] = t[threadIdx.x][threadIdx.y];
}

// ---------------- fold: W2x[plane][tap][d][512c] fp16 hi/lo ----------------
__global__ __launch_bounds__(256) void fold5_k(const float* __restrict__ conv_w,
                                               const float* __restrict__ lwT,
                                               _Float16* __restrict__ W2x) {
    int e0 = blockIdx.x * 8;
    int d = threadIdx.x;
    float acc[8];
    #pragma unroll
    for (int j = 0; j < 8; ++j) acc[j] = 0.f;
    for (int co = 0; co < 256; ++co) {
        float lw = lwT[co * 256 + d];
        const float* cwr = conv_w + (size_t)co * E_ + e0;   // wave-uniform
        #pragma unroll
        for (int j = 0; j < 8; ++j) acc[j] += cwr[j] * lw;
    }
    #pragma unroll
    for (int j = 0; j < 8; ++j) {
        int e = e0 + j;
        int c = e / 9, t9 = e - c * 9;
        _Float16 h = (_Float16)acc[j];
        _Float16 l = (_Float16)(acc[j] - (float)h);
        W2x[((size_t)(t9 * 256 + d)) * 512 + c] = h;
        W2x[((size_t)((9 + t9) * 256 + d)) * 512 + c] = l;
    }
}

__global__ void bias_k(const float* __restrict__ lwT, const float* __restrict__ conv_b,
                       const float* __restrict__ lin_b, float* __restrict__ b2) {
    int d = threadIdx.x;
    float acc = lin_b[d];
    for (int co = 0; co < 256; ++co) acc += lwT[co * 256 + d] * conv_b[co];
    b2[d] = acc;
}

// ---------------- latent -> channel-last fp16 hi/lo planes ----------------
__global__ __launch_bounds__(256) void packlat_k(const float* __restrict__ lat,
                                                 _Float16* __restrict__ Xnp) {
    int b = blockIdx.x, t = threadIdx.x;
    __shared__ float lt[128][65];
    const float* src = lat + (size_t)b * 512 * 64;
    _Float16* dst = Xnp + (size_t)b * 64 * 1024;
    for (int c0 = 0; c0 < 512; c0 += 128) {
        __syncthreads();
        #pragma unroll
        for (int j = 0; j < 8; ++j) {
            int f4 = t + j * 256;
            int cc = f4 >> 4, p4 = (f4 & 15) * 4;
            float4 v = *(const float4*)(src + (size_t)(c0 + cc) * 64 + p4);
            lt[cc][p4] = v.x; lt[cc][p4 + 1] = v.y;
            lt[cc][p4 + 2] = v.z; lt[cc][p4 + 3] = v.w;
        }
        __syncthreads();
        int pix = t >> 2, cr = (t & 3) * 32;
        #pragma unroll
        for (int q = 0; q < 4; ++q) {
            half8_t hh, ll;
            #pragma unroll
            for (int j = 0; j < 8; ++j) {
                float v = lt[cr + q * 8 + j][pix];
                _Float16 h = (_Float16)v;
                hh[j] = h; ll[j] = (_Float16)(v - (float)h);
            }
            *(half8_t*)(dst + (size_t)pix * 1024 + c0 + cr + q * 8) = hh;
            *(half8_t*)(dst + (size_t)pix * 1024 + 512 + c0 + cr + q * 8) = ll;
        }
    }
}

// ---------------- conv MFMA v6: in-LDS tap shifts, A staged once per chunk --
// grid (128 m-tiles, 2 n-halves), 256 thr = 4 waves (2x2 of 64x64).
// LDS 64 KB static: A dbuf 2 x {Ah 8K, Al 8K} + B dbuf 2 x {Bh 8K, Bl 8K}.
// Writes yb ONLY (no A2 fusion -- Xnp is live for other blocks; R9 race).
__global__ __launch_bounds__(256) void convm6_k(
    const _Float16* __restrict__ Xnp, const _Float16* __restrict__ W2x,
    const float* __restrict__ b2, float* __restrict__ yb) {
    __shared__ char sm[65536];
    int m0 = blockIdx.x * 128, n0 = blockIdx.y * 128;
    int tid = threadIdx.x, w = tid >> 6, lane = tid & 63;
    int wm = w & 1, wn = w >> 1;
    int fr = lane & 15, fq = lane >> 4;

    // B fragment-read offsets (convm4-verified slot-permute)
    int xq = (fq ^ ((fr >> 1) & 3)) << 4;
    int boff[4];
    #pragma unroll
    for (int i = 0; i < 4; ++i) boff[i] = (wn * 64 + i * 16 + fr) * 64 + xq;
    // A fragment row geometry: rr = wm*64 + s*16 + fr -> (imgbit, ph, pw)
    int imgoff[4], ph[4], pw[4];
    #pragma unroll
    for (int s = 0; s < 4; ++s) {
        int rr = wm * 64 + s * 16 + fr;
        imgoff[s] = rr & 64; ph[s] = (rr >> 3) & 7; pw[s] = rr & 7;
    }
    // staging slot geometry (2 granules per thread per 8 KB tile)
    int slt[2], sr[2], sq[2];
    #pragma unroll
    for (int i = 0; i < 2; ++i) {
        int s = w * 128 + i * 64 + lane;
        slt[i] = s;
        sr[i] = s >> 2;
        sq[i] = ((s & 3) ^ ((s >> 3) & 3)) * 8;
    }

    auto stageA = [&](int cc, int buf) {
        char* L = sm + buf * 16384;
        #pragma unroll
        for (int i = 0; i < 2; ++i) {
            const _Float16* base =
                Xnp + (size_t)(m0 + sr[i]) * 1024 + cc * 32 + sq[i];
            GLOAD_LDS16(base, L + slt[i] * 16);              // hi plane
            GLOAD_LDS16(base + 512, L + 8192 + slt[i] * 16); // lo plane
        }
    };
    auto stageB = [&](int tap, int cc, int buf) {
        char* L = sm + 32768 + buf * 16384;
        #pragma unroll
        for (int i = 0; i < 2; ++i) {
            const _Float16* bb =
                W2x + ((size_t)(tap * 256 + n0 + sr[i])) * 512 + cc * 32 + sq[i];
            GLOAD_LDS16(bb, L + slt[i] * 16);
            GLOAD_LDS16(bb + (size_t)9 * 256 * 512, L + 8192 + slt[i] * 16);
        }
    };

    f32x4 acc[4][4];
    #pragma unroll
    for (int s = 0; s < 4; ++s)
        #pragma unroll
        for (int t = 0; t < 4; ++t)
            #pragma unroll
            for (int r = 0; r < 4; ++r) acc[s][t][r] = 0.f;

    stageA(0, 0);
    stageB(0, 0, 0);
    const half8_t zfrag = {};
    int gi = 0;
    for (int cc = 0; cc < 16; ++cc) {
        const char* Ab = sm + (cc & 1) * 16384;
        for (int tap = 0; tap < 9; ++tap, ++gi) {
            __syncthreads();
            if (tap < 8) stageB(tap + 1, cc, (gi + 1) & 1);
            else if (cc < 15) stageB(0, cc + 1, (gi + 1) & 1);
            if (tap == 7 && cc < 15) stageA(cc + 1, (cc + 1) & 1);

            int dy = tap / 3 - 1, dx = tap - (tap / 3) * 3 - 1;
            // A fragments: shifted pixels, invalid -> zero
            half8_t ah[4], al[4];
            #pragma unroll
            for (int s = 0; s < 4; ++s) {
                int ih = ph[s] + dy, iw = pw[s] + dx;
                bool v = ((unsigned)ih < 8u) && ((unsigned)iw < 8u);
                int pp = imgoff[s] + (v ? ih * 8 + iw : 0);
                int ao = pp * 64 + ((fq ^ ((pp >> 1) & 3)) << 4);
                half8_t a0 = *(const half8_t*)(Ab + ao);
                half8_t a1 = *(const half8_t*)(Ab + 8192 + ao);
                ah[s] = v ? a0 : zfrag;
                al[s] = v ? a1 : zfrag;
            }
            const char* Bb = sm + 32768 + (gi & 1) * 16384;
            half8_t bh[4], bl[4];
            #pragma unroll
            for (int t = 0; t < 4; ++t) {
                bh[t] = *(const half8_t*)(Bb + boff[t]);
                bl[t] = *(const half8_t*)(Bb + 8192 + boff[t]);
            }
            #pragma unroll
            for (int s = 0; s < 4; ++s)
                #pragma unroll
                for (int t = 0; t < 4; ++t)
                    acc[s][t] = __builtin_amdgcn_mfma_f32_16x16x32_f16(
                        ah[s], bh[t], acc[s][t], 0, 0, 0);
            #pragma unroll
            for (int s = 0; s < 4; ++s)
                #pragma unroll
                for (int t = 0; t < 4; ++t)
                    acc[s][t] = __builtin_amdgcn_mfma_f32_16x16x32_f16(
                        ah[s], bl[t], acc[s][t], 0, 0, 0);
            #pragma unroll
            for (int s = 0; s < 4; ++s)
                #pragma unroll
                for (int t = 0; t < 4; ++t)
                    acc[s][t] = __builtin_amdgcn_mfma_f32_16x16x32_f16(
                        al[s], bh[t], acc[s][t], 0, 0, 0);
        }
    }

    // epilogue: +bias, write yb fp32 only
    float bv[4];
    #pragma unroll
    for (int t = 0; t < 4; ++t) bv[t] = b2[n0 + wn * 64 + t * 16 + fr];
    #pragma unroll
    for (int s = 0; s < 4; ++s)
        #pragma unroll
        for (int r = 0; r < 4; ++r) {
            int m = m0 + wm * 64 + s * 16 + fq * 4 + r;
            #pragma unroll
            for (int t = 0; t < 4; ++t) {
                int d = n0 + wn * 64 + t * 16 + fr;
                yb[(size_t)m * 256 + d] = acc[s][t][r] + bv[t];
            }
        }
}

// ---------------- fused post-conv pack: A2<-yb, B2<-emb, esq<-emb ----------
// 512 blocks x 256 thr. Runs AFTER convm6 (Xnp dead -> A2/B2 regions free).
__global__ __launch_bounds__(256) void pack2_k(
    const float* __restrict__ yb, const float* __restrict__ emb,
    _Float16* __restrict__ A2, _Float16* __restrict__ B2,
    float* __restrict__ esq) {
    // A2 <- yb : 16384 rows x 256 = 1,048,576 float4 groups
    #pragma unroll
    for (int it = 0; it < 8; ++it) {
        int i = (blockIdx.x + it * 512) * 256 + threadIdx.x;
        float4 v = *(const float4*)(yb + (size_t)i * 4);
        half4_t h = {(_Float16)v.x, (_Float16)v.y, (_Float16)v.z, (_Float16)v.w};
        *(half4_t*)(A2 + (size_t)i * 4) = h;
    }
    // B2 + esq <- emb : 8192 rows
    int w = threadIdx.x >> 6, lane = threadIdx.x & 63;
    #pragma unroll
    for (int j = 0; j < 4; ++j) {
        int k = blockIdx.x * 16 + w * 4 + j;
        float4 v = *(const float4*)(emb + (size_t)k * 256 + lane * 4);
        half4_t h = {(_Float16)v.x, (_Float16)v.y, (_Float16)v.z, (_Float16)v.w};
        *(half4_t*)(B2 + (size_t)k * 256 + lane * 4) = h;
        float s = v.x * v.x + v.y * v.y + v.z * v.z + v.w * v.w;
        #pragma unroll
        for (int m = 32; m >= 1; m >>= 1) s += __shfl_xor(s, m, 64);
        if (lane == 0) esq[k] = s;
    }
}

// ---------------- MFMA screen v7: screen6 + XCD-aware remap ----------------
// 1-D grid 8192. xcd = L&7 owns m-tiles [xcd*16, xcd*16+16), n-major sweep.
__global__ __launch_bounds__(256) void screen7_k(
    const _Float16* __restrict__ A2, const _Float16* __restrict__ B2,
    const float* __restrict__ esq, float* __restrict__ ps2, int* __restrict__ pi2) {
    __shared__ char sm[32768];
    int Lb = blockIdx.x;
    int xcd = Lb & 7, j = Lb >> 3;
    int mt = xcd * 16 + (j & 15);
    int nt = j >> 4;
    int m0 = mt * 128, n0 = nt * 128;
    int tid = threadIdx.x, w = tid >> 6, lane = tid & 63;
    int wm = w & 1, wn = w >> 1;
    int fr = lane & 15, fq = lane >> 4;

    int xq = (fq ^ ((fr >> 1) & 3)) << 4;
    int aoff[4], boff[4];
    #pragma unroll
    for (int i = 0; i < 4; ++i) {
        aoff[i] = (wm * 64 + i * 16 + fr) * 64 + xq;
        boff[i] = (wn * 64 + i * 16 + fr) * 64 + xq;
    }
    int slt[2], sr[2], sq[2];
    #pragma unroll
    for (int i = 0; i < 2; ++i) {
        int s = w * 128 + i * 64 + lane;
        slt[i] = s;
        sr[i] = s >> 2;
        sq[i] = ((s & 3) ^ ((s >> 3) & 3)) * 8;
    }

    auto stage = [&](int kt, int buf) {
        char* L = sm + buf * 16384;
        int ko = kt * 32;
        #pragma unroll
        for (int i = 0; i < 2; ++i) {
            GLOAD_LDS16(A2 + (size_t)(m0 + sr[i]) * 256 + ko + sq[i],
                        L + slt[i] * 16);
            GLOAD_LDS16(B2 + (size_t)(n0 + sr[i]) * 256 + ko + sq[i],
                        L + 8192 + slt[i] * 16);
        }
    };

    f32x4 acc[4][4];
    #pragma unroll
    for (int s = 0; s < 4; ++s)
        #pragma unroll
        for (int t = 0; t < 4; ++t)
            #pragma unroll
            for (int r = 0; r < 4; ++r) acc[s][t][r] = 0.f;

    stage(0, 0);
    for (int kt = 0; kt < 8; ++kt) {
        __syncthreads();
        if (kt + 1 < 8) stage(kt + 1, (kt + 1) & 1);
        const char* L = sm + (kt & 1) * 16384;
        half8_t af[4], bf[4];
        #pragma unroll
        for (int s = 0; s < 4; ++s) af[s] = *(const half8_t*)(L + aoff[s]);
        #pragma unroll
        for (int t = 0; t < 4; ++t) bf[t] = *(const half8_t*)(L + 8192 + boff[t]);
        #pragma unroll
        for (int s = 0; s < 4; ++s)
            #pragma unroll
            for (int t = 0; t < 4; ++t)
                acc[s][t] = __builtin_amdgcn_mfma_f32_16x16x32_f16(
                    af[s], bf[t], acc[s][t], 0, 0, 0);
    }

    float esv[4];
    #pragma unroll
    for (int t = 0; t < 4; ++t) esv[t] = esq[n0 + wn * 64 + t * 16 + fr];
    int colIdx = nt * 2 + wn;
    #pragma unroll
    for (int s = 0; s < 4; ++s) {
        #pragma unroll
        for (int r = 0; r < 4; ++r) {
            float best = 3.4e38f; int bidx = 0x7fffffff;
            #pragma unroll
            for (int t = 0; t < 4; ++t) {
                float sc = esv[t] - 2.f * acc[s][t][r];
                int k = n0 + wn * 64 + t * 16 + fr;
                if (sc < best || (sc == best && k < bidx)) { best = sc; bidx = k; }
            }
            #pragma unroll
            for (int msk = 1; msk <= 8; msk <<= 1) {
                float so = __shfl_xor(best, msk, 64);
                int ko2 = __shfl_xor(bidx, msk, 64);
                if (so < best || (so == best && ko2 < bidx)) { best = so; bidx = ko2; }
            }
            if (fr == 0) {
                int m = m0 + wm * 64 + s * 16 + fq * 4 + r;
                ps2[(size_t)m * 128 + colIdx] = best;
                pi2[(size_t)m * 128 + colIdx] = bidx;
            }
        }
    }
}

// ---------------- exact fp32 refine, grid-stride (512 blocks) ----------------
__global__ __launch_bounds__(256) void refine3_k(
    const float* __restrict__ y, const float* __restrict__ emb,
    const float* __restrict__ esq, const float* __restrict__ ps2,
    const int* __restrict__ pi2, int* __restrict__ out) {
    int lane = threadIdx.x & 63;
    for (int j = 0; j < 8; ++j) {
        int m = blockIdx.x * 32 + j * 4 + (threadIdx.x >> 6);
        float4 yv = *(const float4*)(y + (size_t)m * 256 + lane * 4);
        float sc_[2]; int kc_[2];
        #pragma unroll
        for (int i = 0; i < 2; ++i) {
            sc_[i] = ps2[(size_t)m * 128 + lane * 2 + i];
            kc_[i] = pi2[(size_t)m * 128 + lane * 2 + i];
        }
        float s0 = fminf(sc_[0], sc_[1]);
        #pragma unroll
        for (int msk = 1; msk <= 32; msk <<= 1) s0 = fminf(s0, __shfl_xor(s0, msk, 64));
        float thr = s0 + 0.25f;
        float best = 3.4e38f; int bk = 0x7fffffff;
        for (int c = 0; c < 128; ++c) {
            float scc = __shfl(sc_[c & 1], c >> 1, 64);
            if (scc <= thr) {            // wave-uniform
                int k = __shfl(kc_[c & 1], c >> 1, 64);
                float4 ev = *(const float4*)(emb + (size_t)k * 256 + lane * 4);
                float d = yv.x * ev.x + yv.y * ev.y + yv.z * ev.z + yv.w * ev.w;
                #pragma unroll
                for (int msk = 1; msk <= 32; msk <<= 1) d += __shfl_xor(d, msk, 64);
                float sx = esq[k] - 2.f * d;
                if (sx < best || (sx == best && k < bk)) { best = sx; bk = k; }
            }
        }
        if (lane == 0) out[m] = bk;
    }
}

extern "C" void kernel_launch(void* const* d_in, const int* in_sizes, int n_in,
                              void* d_out, int out_size, void* d_ws, size_t ws_size,
                              hipStream_t stream) {
    const float* latent = (const float*)d_in[0];
    const float* conv_w = (const float*)d_in[1];
    const float* conv_b = (const float*)d_in[2];
    const float* lin_w  = (const float*)d_in[3];
    const float* lin_b  = (const float*)d_in[4];
    const float* emb    = (const float*)d_in[5];
    int* out = (int*)d_out;

    char* W = (char*)d_ws;                           // proven 55.35 MB budget
    float*    lwT = (float*)(W + 0);                 //   262,144
    float*    b2  = (float*)(W + 262144);            //     1,024
    float*    esq = (float*)(W + 263168);            //    32,768
    float*    yb  = (float*)(W + 295936);            // 16,777,216
    _Float16* W2x = (_Float16*)(W + 17073152);       //  4,718,592
    _Float16* Xnp = (_Float16*)(W + 21792768);       // 33,554,432 (live: packlat -> convm6)
    // post-conv aliases on the (dead) Xnp region:
    _Float16* A2  = (_Float16*)(W + 21792768);       //  8,388,608 (pack2 -> screen7)
    _Float16* B2  = (_Float16*)(W + 30181376);       //  4,194,304 (pack2 -> screen7)
    float*    ps2 = (float*)(W + 34375680);          //  8,388,608 (screen7 -> refine3)
    int*      pi2 = (int*)(W + 42764288);            //  8,388,608 -> ends 51,152,896

    dim3 t32(32, 32);
    tkern<<<dim3(8, 8), t32, 0, stream>>>(lin_w, lwT, 256, 256);
    bias_k<<<1, 256, 0, stream>>>(lwT, conv_b, lin_b, b2);
    fold5_k<<<576, 256, 0, stream>>>(conv_w, lwT, W2x);
    packlat_k<<<256, 256, 0, stream>>>(latent, Xnp);

    convm6_k<<<dim3(128, 2), 256, 0, stream>>>(Xnp, W2x, b2, yb);

    pack2_k<<<512, 256, 0, stream>>>(yb, emb, A2, B2, esq);   // Xnp dead here
    screen7_k<<<8192, 256, 0, stream>>>(A2, B2, esq, ps2, pi2);
    refine3_k<<<512, 256, 0, stream>>>(yb, emb, esq, ps2, pi2, out);
}